// Round 18
// baseline (9193.038 us; speedup 1.0000x reference)
//
#include <hip/hip_runtime.h>
#include <hip/hip_bf16.h>
#include <math.h>

#define TSEQ 4096
#define EMBD 1024
#define HH   512
#define NTAGS 5
#define NGATE 2048
#define NEGV (-10000.0f)
#define START_TAG 3
#define STOP_TAG 4
#define LSTM_WGS 64
#define PROJ_WGS 1024
#define VIT_BLOCK (LSTM_WGS + PROJ_WGS)

typedef unsigned long long u64;
typedef unsigned int u32;

__device__ __forceinline__ float sigm(float x){ return 1.0f/(1.0f+expf(-x)); }

__device__ __forceinline__ u64 pack_pair(float h, u32 tag){
  return ((u64)tag << 32) | (u64)__float_as_uint(h);
}
__device__ __forceinline__ float rdlane_f(float v, int l){
  return __uint_as_float((u32)__builtin_amdgcn_readlane(__float_as_uint(v), l));
}

// ---------------- init: prime h pair buffers + zero control counters ----------
__global__ void k_init(const float* __restrict__ h0, u64* __restrict__ hx2,
                       int* __restrict__ rdy){
  int tid = threadIdx.x;
  if (tid < 1024){
    int dir = tid >> 9, u = tid & 511;
    hx2[(dir*2 + 0)*HH + u] = pack_pair(h0[dir*HH + u], 0u);
    hx2[(dir*2 + 1)*HH + u] = pack_pair(0.f, 0xFFFFFFFFu);
  }
  if (tid < 96) rdy[tid] = 0;  // [0..63] tile-ready, [65] lstm-done, [66] feats-done
}

// ------- fully fused: BiLSTM + inproj GEMM + feats epilogue + viterbi ----------
// blocks 0..63: lstm (+feats epilogue). 64..1087: inproj GEMM. 1088: viterbi.
// R18: (1) lstm A-prefetch hoisted to TOP of the step loop — previously its
// ~900cyc HBM latency drained inside the next poll's vmcnt(0) (in-order vmcnt).
// (2) viterbi serial loop reduced to fv-evolution only (backpointers recomputed
// bit-identically in a parallel pass from the stored fv history).
__global__ __launch_bounds__(512, 2) void k_fused(
    const int* __restrict__ sent, const float* __restrict__ emb,
    const float* __restrict__ Wif, const float* __restrict__ bf,
    const float* __restrict__ Wib, const float* __restrict__ bb,
    const float* __restrict__ Whf, const float* __restrict__ Whb,
    const float* __restrict__ c0, const float* __restrict__ Wout,
    const float* __restrict__ bout, const float* __restrict__ trans,
    float* __restrict__ A, float* __restrict__ hseq, float* __restrict__ feats,
    int* __restrict__ bpw, float* __restrict__ fvh, float* __restrict__ out,
    u64* __restrict__ hx2, int* __restrict__ rdy){
  __shared__ __align__(16) char smem[17408];
  const int tid = threadIdx.x;

  if (blockIdx.x == VIT_BLOCK){
    // ================= viterbi role (1 wave, lane-parallel rows) =============
    if (tid >= 64) return;
    const int lane = tid;
    while (__hip_atomic_load(&rdy[66], __ATOMIC_ACQUIRE, __HIP_MEMORY_SCOPE_AGENT) < LSTM_WGS)
      __builtin_amdgcn_s_sleep(8);
    float*  sf  = (float*)smem;        // staged feats chunk: 512 steps x 8 = 16KB
    float4* sf4 = (float4*)smem;
    const float4* gf4 = (const float4*)feats;
    const int rr = (lane < 5) ? lane : 0;     // my trellis row
    const float Tr0 = trans[rr*NTAGS+0], Tr1 = trans[rr*NTAGS+1],
                Tr2 = trans[rr*NTAGS+2], Tr3 = trans[rr*NTAGS+3],
                Tr4 = trans[rr*NTAGS+4];
    const float S0=trans[STOP_TAG*NTAGS+0], S1=trans[STOP_TAG*NTAGS+1],
                S2=trans[STOP_TAG*NTAGS+2], S3=trans[STOP_TAG*NTAGS+3],
                S4=trans[STOP_TAG*NTAGS+4];
    float fv0 = NEGV, fv1 = NEGV, fv2 = NEGV, fv3 = 0.f, fv4 = NEGV; // START=3
    // fv history seed: fvh[0][r] = initial state
    if (lane < 5) fvh[lane] = (lane == START_TAG) ? 0.f : NEGV;

    // ---- serial pass: fv evolution only (no bptr work on the chain) ----
    for (int c = 0; c < TSEQ/512; c++){
      #pragma unroll
      for (int i = 0; i < 16; i++)
        sf4[i*64 + lane] = gf4[(size_t)c*1024 + i*64 + lane];
      asm volatile("s_waitcnt vmcnt(0) lgkmcnt(0)" ::: "memory");
      for (int tt = 0; tt < 512; tt++){
        const float featr = sf[tt*8 + rr];            // lane r: feats[t][r]
        const float n0 = fv0 + Tr0, n1 = fv1 + Tr1, n2 = fv2 + Tr2,
                    n3 = fv3 + Tr3, n4 = fv4 + Tr4;
        const float m  = fmaxf(fmaxf(fmaxf(n0, n1), fmaxf(n2, n3)), n4);
        const float nf = m + featr;
        if (lane < 5) fvh[(c*512 + tt + 1)*5 + lane] = nf;   // off-chain store
        fv0 = rdlane_f(nf, 0); fv1 = rdlane_f(nf, 1); fv2 = rdlane_f(nf, 2);
        fv3 = rdlane_f(nf, 3); fv4 = rdlane_f(nf, 4);
      }
    }
    // terminal score/btag from final fv
    int btag;
    {
      const float n0 = fv0 + S0, n1 = fv1 + S1, n2 = fv2 + S2,
                  n3 = fv3 + S3, n4 = fv4 + S4;
      const float m  = fmaxf(fmaxf(fmaxf(n0, n1), fmaxf(n2, n3)), n4);
      btag = (n0 == m) ? 0 : ((n1 == m) ? 1 : ((n2 == m) ? 2 : ((n3 == m) ? 3 : 4)));
      if (lane == 0){ out[0] = m; out[TSEQ] = (float)btag; }
    }
    asm volatile("s_waitcnt vmcnt(0)" ::: "memory");   // fvh stores visible
    // ---- parallel pass: recompute all backpointers bit-identically ----
    {
      const float U00=trans[0],  U01=trans[1],  U02=trans[2],  U03=trans[3],  U04=trans[4];
      const float U10=trans[5],  U11=trans[6],  U12=trans[7],  U13=trans[8],  U14=trans[9];
      const float U20=trans[10], U21=trans[11], U22=trans[12], U23=trans[13], U24=trans[14];
      const float U30=trans[15], U31=trans[16], U32=trans[17], U33=trans[18], U34=trans[19];
      const float U40=trans[20], U41=trans[21], U42=trans[22], U43=trans[23], U44=trans[24];
      for (int base = 0; base < TSEQ; base += 64){
        const int t = base + lane;
        const float f0 = fvh[t*5+0], f1 = fvh[t*5+1], f2 = fvh[t*5+2],
                    f3 = fvh[t*5+3], f4 = fvh[t*5+4];
        int pack;
#define BROW(Ta,Tb,Tc,Td,Te, OUTI)                                          \
        {                                                                   \
          const float n0 = f0 + Ta, n1 = f1 + Tb, n2 = f2 + Tc,             \
                      n3 = f3 + Td, n4 = f4 + Te;                           \
          const float m = fmaxf(fmaxf(fmaxf(n0, n1), fmaxf(n2, n3)), n4);   \
          OUTI = (n0 == m) ? 0 : ((n1 == m) ? 1 : ((n2 == m) ? 2 :          \
                 ((n3 == m) ? 3 : 4)));                                     \
        }
        int i0,i1,i2,i3,i4;
        BROW(U00,U01,U02,U03,U04, i0)
        BROW(U10,U11,U12,U13,U14, i1)
        BROW(U20,U21,U22,U23,U24, i2)
        BROW(U30,U31,U32,U33,U34, i3)
        BROW(U40,U41,U42,U43,U44, i4)
        pack = i0 | (i1<<4) | (i2<<8) | (i3<<12) | (i4<<16);
        bpw[t] = pack;
      }
    }
    asm volatile("s_waitcnt vmcnt(0)" ::: "memory");   // bpw stores visible
    // ---- backtrack (unchanged, validated) ----
    {
      int tag = btag;
      for (int tb = TSEQ - 1; tb >= 1; tb -= 16){
        int w[16];
        #pragma unroll
        for (int i = 0; i < 16; i++){
          const int t = tb - i;
          w[i] = (t >= 1) ? bpw[t] : 0;
        }
        #pragma unroll
        for (int i = 0; i < 16; i++){
          const int t = tb - i;
          if (t >= 1){
            const int prev = (w[i] >> (tag*4)) & 15;
            if (lane == 0) out[t] = (float)prev;
            tag = prev;
          }
        }
      }
    }
    return;
  }

  if (blockIdx.x >= LSTM_WGS){
    // ================= inproj GEMM role =================
    float (*As)[132] = (float(*)[132])smem;              // 16 x 132
    float (*Bs)[132] = (float(*)[132])(smem + 8448);     // 16 x 132
    int* srow        = (int*)(smem + 16896);             // 128
    const int p   = blockIdx.x - LSTM_WGS;               // 0..1023
    const int ti  = p >> 5;                              // 0..31
    const int yy  = p & 31;                              // 0..31
    const int dir = yy >> 4;
    const int t_tile = dir ? (31 - ti) : ti;             // two-ended production
    const int t0  = t_tile * 128;
    const int n0  = (yy & 15) * 128;
    const float* __restrict__ W    = dir ? Wib : Wif;
    const float* __restrict__ bias = dir ? bb : bf;
    if (tid < 128) srow[tid] = sent[t0 + tid];
    __syncthreads();
    const int lr = tid >> 2;            // 0..127
    const int kq = (tid & 3) * 4;
    const float* ea = emb + (size_t)srow[lr]   * EMBD + kq;
    const float* wb = W + (size_t)(n0 + lr)    * EMBD + kq;
    const int tx = tid & 15, ty = tid >> 4;   // ty 0..31
    float acc[4][8];
    #pragma unroll
    for (int i = 0; i < 4; i++)
      #pragma unroll
      for (int j = 0; j < 8; j++) acc[i][j] = 0.f;

    for (int k0 = 0; k0 < EMBD; k0 += 16){
      float4 va = *(const float4*)(ea + k0);
      float4 vb = *(const float4*)(wb + k0);
      As[kq+0][lr] = va.x; As[kq+1][lr] = va.y; As[kq+2][lr] = va.z; As[kq+3][lr] = va.w;
      Bs[kq+0][lr] = vb.x; Bs[kq+1][lr] = vb.y; Bs[kq+2][lr] = vb.z; Bs[kq+3][lr] = vb.w;
      __syncthreads();
      #pragma unroll
      for (int k = 0; k < 16; k++){
        float a[4], b[8];
        *(float4*)&a[0] = *(const float4*)&As[k][ty*4];
        #pragma unroll
        for (int j = 0; j < 8; j++) b[j] = Bs[k][tx + 16*j];
        #pragma unroll
        for (int i = 0; i < 4; i++)
          #pragma unroll
          for (int j = 0; j < 8; j++)
            acc[i][j] = fmaf(a[i], b[j], acc[i][j]);
      }
      __syncthreads();
    }
    float bj[8];
    #pragma unroll
    for (int j = 0; j < 8; j++) bj[j] = bias[n0 + tx + 16*j];
    float* Abase = A + (size_t)dir * TSEQ * NGATE;
    #pragma unroll
    for (int i = 0; i < 4; i++){
      float* dst = Abase + (size_t)(t0 + ty*4 + i) * NGATE + n0 + tx;
      #pragma unroll
      for (int j = 0; j < 8; j++) dst[16*j] = acc[i][j] + bj[j];
    }
    __syncthreads();   // drains every wave's stores (HIP barrier semantics)
    if (tid == 0)
      __hip_atomic_fetch_add(&rdy[dir*32 + t_tile], 1,
                             __ATOMIC_RELEASE, __HIP_MEMORY_SCOPE_AGENT);
    return;
  }

  // ================= persistent lstm role =================
  float* hlbuf = (float*)smem;                 // [2][8*68]
  const int bid  = blockIdx.x;
  const int dir  = bid >> 5;
  const int wg   = bid & 31;
  const int lane = tid & 63;
  const int wv   = tid >> 6;        // wave 0..7 = slice index
  const int ul   = tid >> 5;        // unit local 0..15
  const int g    = (tid >> 3) & 3;  // gate i,f,g,o
  const int q    = tid & 7;         // column octant
  const int unit = wg*16 + ul;
  const float* __restrict__ Wh = dir ? Whb : Whf;

  float wreg[64];                   // Wh[g*512+unit][q*64 .. q*64+63]
  {
    const float* wr = Wh + (size_t)(g*HH + unit)*HH + q*64;
    #pragma unroll
    for (int j4 = 0; j4 < 16; j4++){
      float4 vv;
      // volatile load: result cannot be rematerialized -> stays in VGPRs
      asm volatile("global_load_dwordx4 %0, %1, off\n\t"
                   "s_waitcnt vmcnt(0)"
                   : "=v"(vv) : "v"(wr + 4*j4) : "memory");
      wreg[4*j4+0]=vv.x; wreg[4*j4+1]=vv.y; wreg[4*j4+2]=vv.z; wreg[4*j4+3]=vv.w;
    }
  }
  float creg = 0.f;
  if (g == 0 && q == 0) creg = c0[dir*HH + unit];

  u64* mb = hx2 + (size_t)dir*2*HH;
  const float* __restrict__ Ab = A + (size_t)dir*TSEQ*NGATE;
  const int sidx = (wv << 6) + lane;            // this wave's pair index

  // tile-gate + A prefetch for s=0
  int cur_tile = (dir ? (TSEQ - 1) : 0) >> 7;
  {
    const int* rf = rdy + dir*32 + cur_tile;
    while (__hip_atomic_load(rf, __ATOMIC_ACQUIRE, __HIP_MEMORY_SCOPE_AGENT) < 16)
      __builtin_amdgcn_s_sleep(2);
  }
  float av = 0.f;
  if (q == 0) av = Ab[(size_t)(dir ? (TSEQ - 1) : 0)*NGATE + g*HH + unit];

  for (int s = 0; s < TSEQ; s++){
    const int t = dir ? (TSEQ - 1 - s) : s;

    // HOISTED: prefetch A for step s+1 BEFORE the poll, so its ~900cyc HBM
    // latency resolves under the poll+matvec instead of inside the poll's
    // in-order vmcnt(0) wait.
    float av_next = 0.f;
    if (s + 1 < TSEQ){
      const int t1 = dir ? (TSEQ - 2 - s) : (s + 1);
      const int tile1 = t1 >> 7;
      if (tile1 != cur_tile){
        cur_tile = tile1;
        const int* rf = rdy + dir*32 + tile1;
        while (__hip_atomic_load(rf, __ATOMIC_ACQUIRE, __HIP_MEMORY_SCOPE_AGENT) < 16)
          __builtin_amdgcn_s_sleep(2);
      }
      if (q == 0) av_next = Ab[(size_t)t1*NGATE + g*HH + unit];
    }

    {  // every wave: poll own 64-pair slice (1 load/lane/round, masked reload)
      u64* src = mb + (size_t)(s & 1)*HH;
      const u32 su = (u32)s;
      u64 v = __hip_atomic_load(&src[sidx], __ATOMIC_RELAXED, __HIP_MEMORY_SCOPE_AGENT);
      while (!__all((u32)(v >> 32) == su)){
        if ((u32)(v >> 32) != su)
          v = __hip_atomic_load(&src[sidx], __ATOMIC_RELAXED, __HIP_MEMORY_SCOPE_AGENT);
      }
      hlbuf[(s & 1)*(8*68) + wv*68 + lane] = __uint_as_float((u32)v);
    }
    __syncthreads();

    // matvec: 64 FMAs from LDS chunk q (weights register-resident)
    const float* hq = hlbuf + (s & 1)*(8*68) + q*68;
    float p0 = 0.f, p1 = 0.f, p2 = 0.f, p3 = 0.f;
    #pragma unroll
    for (int j4 = 0; j4 < 16; j4++){
      float4 h4 = *(const float4*)(hq + 4*j4);
      p0 = fmaf(wreg[4*j4+0], h4.x, p0);
      p1 = fmaf(wreg[4*j4+1], h4.y, p1);
      p2 = fmaf(wreg[4*j4+2], h4.z, p2);
      p3 = fmaf(wreg[4*j4+3], h4.w, p3);
    }
    float acc = ((p0 + p1) + (p2 + p3)) + av;
    acc += __shfl_xor(acc, 1);
    acc += __shfl_xor(acc, 2);
    acc += __shfl_xor(acc, 4);
    // parallel nonlinearity: one transcendental per gate lane
    const float act = (g == 2) ? tanhf(acc) : sigm(acc);
    const float f_ = __shfl_down(act, 8);
    const float g_ = __shfl_down(act, 16);
    const float o_ = __shfl_down(act, 24);
    if (g == 0 && q == 0){
      const float c2 = f_*creg + act*g_;
      const float h2 = o_*tanhf(c2);
      creg = c2;
      // publish FIRST (critical path), bookkeeping store after
      __hip_atomic_store(&mb[(size_t)((s + 1) & 1)*HH + unit], pack_pair(h2, (u32)(s + 1)),
                         __ATOMIC_RELAXED, __HIP_MEMORY_SCOPE_AGENT);
      hseq[((size_t)dir*TSEQ + t)*HH + unit] = h2;
    }
    av = av_next;
  }

  // ---------- feats epilogue: wait for all 64 lstm blocks, then 64 t-rows ------
  __syncthreads();   // all this block's hseq stores issued
  if (tid == 0)
    __hip_atomic_fetch_add(&rdy[65], 1, __ATOMIC_RELEASE, __HIP_MEMORY_SCOPE_AGENT);
  while (__hip_atomic_load(&rdy[65], __ATOMIC_ACQUIRE, __HIP_MEMORY_SCOPE_AGENT) < LSTM_WGS)
    __builtin_amdgcn_s_sleep(2);
  {
    const int wvi = tid >> 6;    // wave 0..7, each does 8 t values
    #pragma unroll
    for (int k = 0; k < 8; k++){
      const int t = bid*64 + wvi*8 + k;
      const float* hf = hseq + (size_t)t*HH;
      const float* hb = hseq + (size_t)(TSEQ + t)*HH;
      float x[16];
      #pragma unroll
      for (int j = 0; j < 8; j++) x[j]     = hf[lane + 64*j];
      #pragma unroll
      for (int j = 0; j < 8; j++) x[8 + j] = hb[lane + 64*j];
      #pragma unroll
      for (int n = 0; n < NTAGS; n++){
        const float* wr = Wout + (size_t)n*(2*HH);
        float p = 0.f;
        #pragma unroll
        for (int j = 0; j < 8; j++) p = fmaf(x[j],     wr[lane + 64*j],      p);
        #pragma unroll
        for (int j = 0; j < 8; j++) p = fmaf(x[8 + j], wr[HH + lane + 64*j], p);
        #pragma unroll
        for (int d = 1; d < 64; d <<= 1) p += __shfl_xor(p, d);
        if (lane == 0) feats[t*8 + n] = p + bout[n];
      }
    }
  }
  __syncthreads();   // all this block's feats stores issued
  if (tid == 0)
    __hip_atomic_fetch_add(&rdy[66], 1, __ATOMIC_RELEASE, __HIP_MEMORY_SCOPE_AGENT);
}

extern "C" void kernel_launch(void* const* d_in, const int* in_sizes, int n_in,
                              void* d_out, int out_size, void* d_ws, size_t ws_size,
                              hipStream_t stream) {
  const int*   sent = (const int*)  d_in[0];
  const float* emb  = (const float*)d_in[1];
  const float* Wihf = (const float*)d_in[2];
  const float* Whhf = (const float*)d_in[3];
  const float* bf_  = (const float*)d_in[4];
  const float* Wihb = (const float*)d_in[5];
  const float* Whhb = (const float*)d_in[6];
  const float* bb_  = (const float*)d_in[7];
  const float* Wout = (const float*)d_in[8];
  const float* bout = (const float*)d_in[9];
  const float* trans= (const float*)d_in[10];
  const float* h0   = (const float*)d_in[11];
  const float* c0   = (const float*)d_in[12];
  float* out = (float*)d_out;

  float* ws   = (float*)d_ws;
  float* A    = ws;                                  // [2][T][2048]
  float* hseq = A    + (size_t)2*TSEQ*NGATE;         // [2][T][512]
  u64*   hx2  = (u64*)(hseq + (size_t)2*TSEQ*HH);    // [2][2][512] (tag,val) pairs
  float* fe   = (float*)(hx2 + 2048);                // [T][8]
  int*   bpw  = (int*)(fe + (size_t)TSEQ*8);         // [T] packed nibbles
  int*   rdy  = bpw + TSEQ;                          // [64] tile-ready + [65][66]
  float* fvh  = (float*)(rdy + 96);                  // [T+1][5] fv history
  (void)ws_size;

  k_init<<<1, 1024, 0, stream>>>(h0, hx2, rdy);
  k_fused<<<VIT_BLOCK + 1, 512, 0, stream>>>(
      sent, emb, Wihf, bf_, Wihb, bb_, Whhf, Whhb, c0, Wout, bout, trans,
      A, hseq, fe, bpw, fvh, out, hx2, rdy);
}

// Round 19
// 7950.169 us; speedup vs baseline: 1.1563x; 1.1563x over previous
//
#include <hip/hip_runtime.h>
#include <hip/hip_bf16.h>
#include <math.h>

#define TSEQ 4096
#define EMBD 1024
#define HH   512
#define NTAGS 5
#define NGATE 2048
#define NEGV (-10000.0f)
#define START_TAG 3
#define STOP_TAG 4
#define LSTM_WGS 64
#define PROJ_WGS 1024
#define VIT_BLOCK (LSTM_WGS + PROJ_WGS)

typedef unsigned long long u64;
typedef unsigned int u32;

__device__ __forceinline__ float sigm(float x){ return 1.0f/(1.0f+expf(-x)); }

__device__ __forceinline__ u64 pack_pair(float h, u32 tag){
  return ((u64)tag << 32) | (u64)__float_as_uint(h);
}
__device__ __forceinline__ float rdlane_f(float v, int l){
  return __uint_as_float((u32)__builtin_amdgcn_readlane(__float_as_uint(v), l));
}

// ---------------- init: prime h pair buffers + zero control counters ----------
__global__ void k_init(const float* __restrict__ h0, u64* __restrict__ hx2,
                       int* __restrict__ rdy){
  int tid = threadIdx.x;
  if (tid < 1024){
    int dir = tid >> 9, u = tid & 511;
    hx2[(dir*2 + 0)*HH + u] = pack_pair(h0[dir*HH + u], 0u);
    hx2[(dir*2 + 1)*HH + u] = pack_pair(0.f, 0xFFFFFFFFu);
  }
  if (tid < 96) rdy[tid] = 0;  // [0..63] tile-ready, [65] lstm-done, [66] feats-done
}

// ------- fully fused: BiLSTM + inproj GEMM + feats epilogue + viterbi ----------
// blocks 0..63: lstm (+feats epilogue). 64..1087: inproj GEMM. 1088: viterbi.
// R19: lstm loop reverted EXACTLY to R17 (R18's A-prefetch hoist put the HBM
// load right before the poll's first vmcnt(0) drain -> +380cyc/step; R17's
// post-barrier placement lets the spin-loop hide it). Single change vs R17:
// viterbi feat read software-pipelined one step ahead — the ~120cyc LDS load
// was on the serial fv chain (0.67ms was LDS-latency-bound).
__global__ __launch_bounds__(512, 2) void k_fused(
    const int* __restrict__ sent, const float* __restrict__ emb,
    const float* __restrict__ Wif, const float* __restrict__ bf,
    const float* __restrict__ Wib, const float* __restrict__ bb,
    const float* __restrict__ Whf, const float* __restrict__ Whb,
    const float* __restrict__ c0, const float* __restrict__ Wout,
    const float* __restrict__ bout, const float* __restrict__ trans,
    float* __restrict__ A, float* __restrict__ hseq, float* __restrict__ feats,
    int* __restrict__ bpw, float* __restrict__ out,
    u64* __restrict__ hx2, int* __restrict__ rdy){
  __shared__ __align__(16) char smem[17408];
  const int tid = threadIdx.x;

  if (blockIdx.x == VIT_BLOCK){
    // ================= viterbi role (1 wave, lane-parallel rows) =============
    if (tid >= 64) return;
    const int lane = tid;
    while (__hip_atomic_load(&rdy[66], __ATOMIC_ACQUIRE, __HIP_MEMORY_SCOPE_AGENT) < LSTM_WGS)
      __builtin_amdgcn_s_sleep(8);
    float*  sf  = (float*)smem;        // staged feats chunk: 512 steps x 8 = 16KB
    float4* sf4 = (float4*)smem;
    const float4* gf4 = (const float4*)feats;
    const int rr = (lane < 5) ? lane : 0;     // my trellis row
    const float Tr0 = trans[rr*NTAGS+0], Tr1 = trans[rr*NTAGS+1],
                Tr2 = trans[rr*NTAGS+2], Tr3 = trans[rr*NTAGS+3],
                Tr4 = trans[rr*NTAGS+4];
    const float S0=trans[STOP_TAG*NTAGS+0], S1=trans[STOP_TAG*NTAGS+1],
                S2=trans[STOP_TAG*NTAGS+2], S3=trans[STOP_TAG*NTAGS+3],
                S4=trans[STOP_TAG*NTAGS+4];
    float fv0 = NEGV, fv1 = NEGV, fv2 = NEGV, fv3 = 0.f, fv4 = NEGV; // START=3

    for (int c = 0; c < TSEQ/512; c++){
      // stage 512 steps (1024 float4) coalesced: lane does 16 float4
      #pragma unroll
      for (int i = 0; i < 16; i++)
        sf4[i*64 + lane] = gf4[(size_t)c*1024 + i*64 + lane];
      asm volatile("s_waitcnt vmcnt(0) lgkmcnt(0)" ::: "memory");
      // feat pipelined one step ahead: LDS latency off the serial fv chain
      float featr = sf[rr];
      for (int tt = 0; tt < 512; tt++){
        const float featr_nx = sf[(tt + 1)*8 + rr];  // prefetch (tt=511 over-read
                                                     // stays in smem, discarded)
        const float n0 = fv0 + Tr0, n1 = fv1 + Tr1, n2 = fv2 + Tr2,
                    n3 = fv3 + Tr3, n4 = fv4 + Tr4;
        const float m  = fmaxf(fmaxf(fmaxf(n0, n1), fmaxf(n2, n3)), n4);
        const int idx  = (n0 == m) ? 0 : ((n1 == m) ? 1 : ((n2 == m) ? 2 :
                         ((n3 == m) ? 3 : 4)));
        const float nf = m + featr;
        fv0 = rdlane_f(nf, 0); fv1 = rdlane_f(nf, 1); fv2 = rdlane_f(nf, 2);
        fv3 = rdlane_f(nf, 3); fv4 = rdlane_f(nf, 4);
        const int i0 = __builtin_amdgcn_readlane(idx, 0);
        const int i1 = __builtin_amdgcn_readlane(idx, 1);
        const int i2 = __builtin_amdgcn_readlane(idx, 2);
        const int i3 = __builtin_amdgcn_readlane(idx, 3);
        const int i4 = __builtin_amdgcn_readlane(idx, 4);
        const int pack = i0 | (i1<<4) | (i2<<8) | (i3<<12) | (i4<<16);
        if (lane == 0) bpw[c*512 + tt] = pack;
        featr = featr_nx;
      }
    }
    {
      const float n0 = fv0 + S0, n1 = fv1 + S1, n2 = fv2 + S2,
                  n3 = fv3 + S3, n4 = fv4 + S4;
      const float m  = fmaxf(fmaxf(fmaxf(n0, n1), fmaxf(n2, n3)), n4);
      const int btag = (n0 == m) ? 0 : ((n1 == m) ? 1 : ((n2 == m) ? 2 : ((n3 == m) ? 3 : 4)));
      if (lane == 0){ out[0] = m; out[TSEQ] = (float)btag; }
      int tag = btag;
      for (int tb = TSEQ - 1; tb >= 1; tb -= 16){
        int w[16];
        #pragma unroll
        for (int i = 0; i < 16; i++){
          const int t = tb - i;
          w[i] = (t >= 1) ? bpw[t] : 0;
        }
        #pragma unroll
        for (int i = 0; i < 16; i++){
          const int t = tb - i;
          if (t >= 1){
            const int prev = (w[i] >> (tag*4)) & 15;
            if (lane == 0) out[t] = (float)prev;
            tag = prev;
          }
        }
      }
    }
    return;
  }

  if (blockIdx.x >= LSTM_WGS){
    // ================= inproj GEMM role =================
    float (*As)[132] = (float(*)[132])smem;              // 16 x 132
    float (*Bs)[132] = (float(*)[132])(smem + 8448);     // 16 x 132
    int* srow        = (int*)(smem + 16896);             // 128
    const int p   = blockIdx.x - LSTM_WGS;               // 0..1023
    const int ti  = p >> 5;                              // 0..31
    const int yy  = p & 31;                              // 0..31
    const int dir = yy >> 4;
    const int t_tile = dir ? (31 - ti) : ti;             // two-ended production
    const int t0  = t_tile * 128;
    const int n0  = (yy & 15) * 128;
    const float* __restrict__ W    = dir ? Wib : Wif;
    const float* __restrict__ bias = dir ? bb : bf;
    if (tid < 128) srow[tid] = sent[t0 + tid];
    __syncthreads();
    const int lr = tid >> 2;            // 0..127
    const int kq = (tid & 3) * 4;
    const float* ea = emb + (size_t)srow[lr]   * EMBD + kq;
    const float* wb = W + (size_t)(n0 + lr)    * EMBD + kq;
    const int tx = tid & 15, ty = tid >> 4;   // ty 0..31
    float acc[4][8];
    #pragma unroll
    for (int i = 0; i < 4; i++)
      #pragma unroll
      for (int j = 0; j < 8; j++) acc[i][j] = 0.f;

    for (int k0 = 0; k0 < EMBD; k0 += 16){
      float4 va = *(const float4*)(ea + k0);
      float4 vb = *(const float4*)(wb + k0);
      As[kq+0][lr] = va.x; As[kq+1][lr] = va.y; As[kq+2][lr] = va.z; As[kq+3][lr] = va.w;
      Bs[kq+0][lr] = vb.x; Bs[kq+1][lr] = vb.y; Bs[kq+2][lr] = vb.z; Bs[kq+3][lr] = vb.w;
      __syncthreads();
      #pragma unroll
      for (int k = 0; k < 16; k++){
        float a[4], b[8];
        *(float4*)&a[0] = *(const float4*)&As[k][ty*4];
        #pragma unroll
        for (int j = 0; j < 8; j++) b[j] = Bs[k][tx + 16*j];
        #pragma unroll
        for (int i = 0; i < 4; i++)
          #pragma unroll
          for (int j = 0; j < 8; j++)
            acc[i][j] = fmaf(a[i], b[j], acc[i][j]);
      }
      __syncthreads();
    }
    float bj[8];
    #pragma unroll
    for (int j = 0; j < 8; j++) bj[j] = bias[n0 + tx + 16*j];
    float* Abase = A + (size_t)dir * TSEQ * NGATE;
    #pragma unroll
    for (int i = 0; i < 4; i++){
      float* dst = Abase + (size_t)(t0 + ty*4 + i) * NGATE + n0 + tx;
      #pragma unroll
      for (int j = 0; j < 8; j++) dst[16*j] = acc[i][j] + bj[j];
    }
    __syncthreads();   // drains every wave's stores (HIP barrier semantics)
    if (tid == 0)
      __hip_atomic_fetch_add(&rdy[dir*32 + t_tile], 1,
                             __ATOMIC_RELEASE, __HIP_MEMORY_SCOPE_AGENT);
    return;
  }

  // ================= persistent lstm role (R17, validated) =================
  float* hlbuf = (float*)smem;                 // [2][8*68]
  const int bid  = blockIdx.x;
  const int dir  = bid >> 5;
  const int wg   = bid & 31;
  const int lane = tid & 63;
  const int wv   = tid >> 6;        // wave 0..7 = slice index
  const int ul   = tid >> 5;        // unit local 0..15
  const int g    = (tid >> 3) & 3;  // gate i,f,g,o
  const int q    = tid & 7;         // column octant
  const int unit = wg*16 + ul;
  const float* __restrict__ Wh = dir ? Whb : Whf;

  float wreg[64];                   // Wh[g*512+unit][q*64 .. q*64+63]
  {
    const float* wr = Wh + (size_t)(g*HH + unit)*HH + q*64;
    #pragma unroll
    for (int j4 = 0; j4 < 16; j4++){
      float4 vv;
      // volatile load: result cannot be rematerialized -> stays in VGPRs
      asm volatile("global_load_dwordx4 %0, %1, off\n\t"
                   "s_waitcnt vmcnt(0)"
                   : "=v"(vv) : "v"(wr + 4*j4) : "memory");
      wreg[4*j4+0]=vv.x; wreg[4*j4+1]=vv.y; wreg[4*j4+2]=vv.z; wreg[4*j4+3]=vv.w;
    }
  }
  float creg = 0.f;
  if (g == 0 && q == 0) creg = c0[dir*HH + unit];

  u64* mb = hx2 + (size_t)dir*2*HH;
  const float* __restrict__ Ab = A + (size_t)dir*TSEQ*NGATE;
  const int sidx = (wv << 6) + lane;            // this wave's pair index

  // tile-gate + A prefetch for s=0
  int cur_tile = (dir ? (TSEQ - 1) : 0) >> 7;
  {
    const int* rf = rdy + dir*32 + cur_tile;
    while (__hip_atomic_load(rf, __ATOMIC_ACQUIRE, __HIP_MEMORY_SCOPE_AGENT) < 16)
      __builtin_amdgcn_s_sleep(2);
  }
  float av = 0.f;
  if (q == 0) av = Ab[(size_t)(dir ? (TSEQ - 1) : 0)*NGATE + g*HH + unit];

  for (int s = 0; s < TSEQ; s++){
    const int t = dir ? (TSEQ - 1 - s) : s;

    {  // every wave: poll own 64-pair slice (1 load/lane/round, masked reload)
      u64* src = mb + (size_t)(s & 1)*HH;
      const u32 su = (u32)s;
      u64 v = __hip_atomic_load(&src[sidx], __ATOMIC_RELAXED, __HIP_MEMORY_SCOPE_AGENT);
      while (!__all((u32)(v >> 32) == su)){
        if ((u32)(v >> 32) != su)
          v = __hip_atomic_load(&src[sidx], __ATOMIC_RELAXED, __HIP_MEMORY_SCOPE_AGENT);
      }
      hlbuf[(s & 1)*(8*68) + wv*68 + lane] = __uint_as_float((u32)v);
    }
    __syncthreads();

    // prefetch A for step s+1 (resolves under the matvec, off the poll path)
    float av_next = 0.f;
    if (s + 1 < TSEQ){
      const int t1 = dir ? (TSEQ - 2 - s) : (s + 1);
      const int tile1 = t1 >> 7;
      if (tile1 != cur_tile){
        cur_tile = tile1;
        const int* rf = rdy + dir*32 + tile1;
        while (__hip_atomic_load(rf, __ATOMIC_ACQUIRE, __HIP_MEMORY_SCOPE_AGENT) < 16)
          __builtin_amdgcn_s_sleep(2);
      }
      if (q == 0) av_next = Ab[(size_t)t1*NGATE + g*HH + unit];
    }

    // matvec: 64 FMAs from LDS chunk q (weights register-resident)
    const float* hq = hlbuf + (s & 1)*(8*68) + q*68;
    float p0 = 0.f, p1 = 0.f, p2 = 0.f, p3 = 0.f;
    #pragma unroll
    for (int j4 = 0; j4 < 16; j4++){
      float4 h4 = *(const float4*)(hq + 4*j4);
      p0 = fmaf(wreg[4*j4+0], h4.x, p0);
      p1 = fmaf(wreg[4*j4+1], h4.y, p1);
      p2 = fmaf(wreg[4*j4+2], h4.z, p2);
      p3 = fmaf(wreg[4*j4+3], h4.w, p3);
    }
    float acc = ((p0 + p1) + (p2 + p3)) + av;
    acc += __shfl_xor(acc, 1);
    acc += __shfl_xor(acc, 2);
    acc += __shfl_xor(acc, 4);
    // parallel nonlinearity: one transcendental per gate lane
    const float act = (g == 2) ? tanhf(acc) : sigm(acc);
    const float f_ = __shfl_down(act, 8);
    const float g_ = __shfl_down(act, 16);
    const float o_ = __shfl_down(act, 24);
    if (g == 0 && q == 0){
      const float c2 = f_*creg + act*g_;
      const float h2 = o_*tanhf(c2);
      creg = c2;
      // publish FIRST (critical path), bookkeeping store after
      __hip_atomic_store(&mb[(size_t)((s + 1) & 1)*HH + unit], pack_pair(h2, (u32)(s + 1)),
                         __ATOMIC_RELAXED, __HIP_MEMORY_SCOPE_AGENT);
      hseq[((size_t)dir*TSEQ + t)*HH + unit] = h2;
    }
    av = av_next;
  }

  // ---------- feats epilogue: wait for all 64 lstm blocks, then 64 t-rows ------
  __syncthreads();   // all this block's hseq stores issued
  if (tid == 0)
    __hip_atomic_fetch_add(&rdy[65], 1, __ATOMIC_RELEASE, __HIP_MEMORY_SCOPE_AGENT);
  while (__hip_atomic_load(&rdy[65], __ATOMIC_ACQUIRE, __HIP_MEMORY_SCOPE_AGENT) < LSTM_WGS)
    __builtin_amdgcn_s_sleep(2);
  {
    const int wvi = tid >> 6;    // wave 0..7, each does 8 t values
    #pragma unroll
    for (int k = 0; k < 8; k++){
      const int t = bid*64 + wvi*8 + k;
      const float* hf = hseq + (size_t)t*HH;
      const float* hb = hseq + (size_t)(TSEQ + t)*HH;
      float x[16];
      #pragma unroll
      for (int j = 0; j < 8; j++) x[j]     = hf[lane + 64*j];
      #pragma unroll
      for (int j = 0; j < 8; j++) x[8 + j] = hb[lane + 64*j];
      #pragma unroll
      for (int n = 0; n < NTAGS; n++){
        const float* wr = Wout + (size_t)n*(2*HH);
        float p = 0.f;
        #pragma unroll
        for (int j = 0; j < 8; j++) p = fmaf(x[j],     wr[lane + 64*j],      p);
        #pragma unroll
        for (int j = 0; j < 8; j++) p = fmaf(x[8 + j], wr[HH + lane + 64*j], p);
        #pragma unroll
        for (int d = 1; d < 64; d <<= 1) p += __shfl_xor(p, d);
        if (lane == 0) feats[t*8 + n] = p + bout[n];
      }
    }
  }
  __syncthreads();   // all this block's feats stores issued
  if (tid == 0)
    __hip_atomic_fetch_add(&rdy[66], 1, __ATOMIC_RELEASE, __HIP_MEMORY_SCOPE_AGENT);
}

extern "C" void kernel_launch(void* const* d_in, const int* in_sizes, int n_in,
                              void* d_out, int out_size, void* d_ws, size_t ws_size,
                              hipStream_t stream) {
  const int*   sent = (const int*)  d_in[0];
  const float* emb  = (const float*)d_in[1];
  const float* Wihf = (const float*)d_in[2];
  const float* Whhf = (const float*)d_in[3];
  const float* bf_  = (const float*)d_in[4];
  const float* Wihb = (const float*)d_in[5];
  const float* Whhb = (const float*)d_in[6];
  const float* bb_  = (const float*)d_in[7];
  const float* Wout = (const float*)d_in[8];
  const float* bout = (const float*)d_in[9];
  const float* trans= (const float*)d_in[10];
  const float* h0   = (const float*)d_in[11];
  const float* c0   = (const float*)d_in[12];
  float* out = (float*)d_out;

  float* ws   = (float*)d_ws;
  float* A    = ws;                                  // [2][T][2048]
  float* hseq = A    + (size_t)2*TSEQ*NGATE;         // [2][T][512]
  u64*   hx2  = (u64*)(hseq + (size_t)2*TSEQ*HH);    // [2][2][512] (tag,val) pairs
  float* fe   = (float*)(hx2 + 2048);                // [T][8]
  int*   bpw  = (int*)(fe + (size_t)TSEQ*8);         // [T] packed nibbles
  int*   rdy  = bpw + TSEQ;                          // [64] tile-ready + [65][66]
  (void)ws_size;

  k_init<<<1, 1024, 0, stream>>>(h0, hx2, rdy);
  k_fused<<<VIT_BLOCK + 1, 512, 0, stream>>>(
      sent, emb, Wihf, bf_, Wihb, bb_, Whhf, Whhb, c0, Wout, bout, trans,
      A, hseq, fe, bpw, out, hx2, rdy);
}

// Round 20
// 7850.776 us; speedup vs baseline: 1.1710x; 1.0127x over previous
//
#include <hip/hip_runtime.h>
#include <hip/hip_bf16.h>
#include <math.h>

#define TSEQ 4096
#define EMBD 1024
#define HH   512
#define NTAGS 5
#define NGATE 2048
#define NEGV (-10000.0f)
#define START_TAG 3
#define STOP_TAG 4
#define LSTM_WGS 64
#define PROJ_WGS 1024
#define VIT_BLOCK (LSTM_WGS + PROJ_WGS)

typedef unsigned long long u64;
typedef unsigned int u32;

__device__ __forceinline__ float sigm(float x){ return 1.0f/(1.0f+expf(-x)); }

__device__ __forceinline__ u64 pack_pair(float h, u32 tag){
  return ((u64)tag << 32) | (u64)__float_as_uint(h);
}
__device__ __forceinline__ float rdlane_f(float v, int l){
  return __uint_as_float((u32)__builtin_amdgcn_readlane(__float_as_uint(v), l));
}

// ---------------- init: prime h pair buffers + zero control counters ----------
__global__ void k_init(const float* __restrict__ h0, u64* __restrict__ hx2,
                       int* __restrict__ rdy){
  int tid = threadIdx.x;
  if (tid < 1024){
    int dir = tid >> 9, u = tid & 511;
    hx2[(dir*2 + 0)*HH + u] = pack_pair(h0[dir*HH + u], 0u);
    hx2[(dir*2 + 1)*HH + u] = pack_pair(0.f, 0xFFFFFFFFu);
  }
  if (tid < 96) rdy[tid] = 0;  // [0..63] tile-ready, [65] lstm-done, [66] feats-done
}

// ------- fully fused: BiLSTM + inproj GEMM + feats epilogue + viterbi ----------
// blocks 0..63: lstm (+feats epilogue). 64..1087: inproj GEMM. 1088: viterbi.
// R20: (1) COALESCED PUBLISH — owners gather h2 into LDS, one barrier, wave 0
// issues ONE 128B pair-store per WG (vs 512 scattered 8B agent stores/step/dir,
// whose sub-line RMW serialization at the coherence point is the candidate for
// the unexplained ~1200cyc/step). Causality unchanged. (2) viterbi fvh-split
// (R18 component, passed): serial loop = fv-evolution only; backpointers
// recomputed bit-identically in a parallel pass.
__global__ __launch_bounds__(512, 2) void k_fused(
    const int* __restrict__ sent, const float* __restrict__ emb,
    const float* __restrict__ Wif, const float* __restrict__ bf,
    const float* __restrict__ Wib, const float* __restrict__ bb,
    const float* __restrict__ Whf, const float* __restrict__ Whb,
    const float* __restrict__ c0, const float* __restrict__ Wout,
    const float* __restrict__ bout, const float* __restrict__ trans,
    float* __restrict__ A, float* __restrict__ hseq, float* __restrict__ feats,
    int* __restrict__ bpw, float* __restrict__ fvh, float* __restrict__ out,
    u64* __restrict__ hx2, int* __restrict__ rdy){
  __shared__ __align__(16) char smem[17408];
  const int tid = threadIdx.x;

  if (blockIdx.x == VIT_BLOCK){
    // ================= viterbi role (1 wave, lane-parallel rows) =============
    if (tid >= 64) return;
    const int lane = tid;
    while (__hip_atomic_load(&rdy[66], __ATOMIC_ACQUIRE, __HIP_MEMORY_SCOPE_AGENT) < LSTM_WGS)
      __builtin_amdgcn_s_sleep(8);
    float*  sf  = (float*)smem;        // staged feats chunk: 512 steps x 8 = 16KB
    float4* sf4 = (float4*)smem;
    const float4* gf4 = (const float4*)feats;
    const int rr = (lane < 5) ? lane : 0;     // my trellis row
    const float Tr0 = trans[rr*NTAGS+0], Tr1 = trans[rr*NTAGS+1],
                Tr2 = trans[rr*NTAGS+2], Tr3 = trans[rr*NTAGS+3],
                Tr4 = trans[rr*NTAGS+4];
    const float S0=trans[STOP_TAG*NTAGS+0], S1=trans[STOP_TAG*NTAGS+1],
                S2=trans[STOP_TAG*NTAGS+2], S3=trans[STOP_TAG*NTAGS+3],
                S4=trans[STOP_TAG*NTAGS+4];
    float fv0 = NEGV, fv1 = NEGV, fv2 = NEGV, fv3 = 0.f, fv4 = NEGV; // START=3
    if (lane < 5) fvh[lane] = (lane == START_TAG) ? 0.f : NEGV;

    // ---- serial pass: fv evolution only (no bptr work on the chain) ----
    for (int c = 0; c < TSEQ/512; c++){
      #pragma unroll
      for (int i = 0; i < 16; i++)
        sf4[i*64 + lane] = gf4[(size_t)c*1024 + i*64 + lane];
      asm volatile("s_waitcnt vmcnt(0) lgkmcnt(0)" ::: "memory");
      for (int tt = 0; tt < 512; tt++){
        const float featr = sf[tt*8 + rr];            // lane r: feats[t][r]
        const float n0 = fv0 + Tr0, n1 = fv1 + Tr1, n2 = fv2 + Tr2,
                    n3 = fv3 + Tr3, n4 = fv4 + Tr4;
        const float m  = fmaxf(fmaxf(fmaxf(n0, n1), fmaxf(n2, n3)), n4);
        const float nf = m + featr;
        if (lane < 5) fvh[(c*512 + tt + 1)*5 + lane] = nf;   // off-chain store
        fv0 = rdlane_f(nf, 0); fv1 = rdlane_f(nf, 1); fv2 = rdlane_f(nf, 2);
        fv3 = rdlane_f(nf, 3); fv4 = rdlane_f(nf, 4);
      }
    }
    // terminal score/btag from final fv
    int btag;
    {
      const float n0 = fv0 + S0, n1 = fv1 + S1, n2 = fv2 + S2,
                  n3 = fv3 + S3, n4 = fv4 + S4;
      const float m  = fmaxf(fmaxf(fmaxf(n0, n1), fmaxf(n2, n3)), n4);
      btag = (n0 == m) ? 0 : ((n1 == m) ? 1 : ((n2 == m) ? 2 : ((n3 == m) ? 3 : 4)));
      if (lane == 0){ out[0] = m; out[TSEQ] = (float)btag; }
    }
    asm volatile("s_waitcnt vmcnt(0)" ::: "memory");   // fvh stores visible
    // ---- parallel pass: recompute all backpointers bit-identically ----
    {
      const float U00=trans[0],  U01=trans[1],  U02=trans[2],  U03=trans[3],  U04=trans[4];
      const float U10=trans[5],  U11=trans[6],  U12=trans[7],  U13=trans[8],  U14=trans[9];
      const float U20=trans[10], U21=trans[11], U22=trans[12], U23=trans[13], U24=trans[14];
      const float U30=trans[15], U31=trans[16], U32=trans[17], U33=trans[18], U34=trans[19];
      const float U40=trans[20], U41=trans[21], U42=trans[22], U43=trans[23], U44=trans[24];
      for (int base = 0; base < TSEQ; base += 64){
        const int t = base + lane;
        const float f0 = fvh[t*5+0], f1 = fvh[t*5+1], f2 = fvh[t*5+2],
                    f3 = fvh[t*5+3], f4 = fvh[t*5+4];
#define BROW(Ta,Tb,Tc,Td,Te, OUTI)                                          \
        {                                                                   \
          const float n0 = f0 + Ta, n1 = f1 + Tb, n2 = f2 + Tc,             \
                      n3 = f3 + Td, n4 = f4 + Te;                           \
          const float m = fmaxf(fmaxf(fmaxf(n0, n1), fmaxf(n2, n3)), n4);   \
          OUTI = (n0 == m) ? 0 : ((n1 == m) ? 1 : ((n2 == m) ? 2 :          \
                 ((n3 == m) ? 3 : 4)));                                     \
        }
        int i0,i1,i2,i3,i4;
        BROW(U00,U01,U02,U03,U04, i0)
        BROW(U10,U11,U12,U13,U14, i1)
        BROW(U20,U21,U22,U23,U24, i2)
        BROW(U30,U31,U32,U33,U34, i3)
        BROW(U40,U41,U42,U43,U44, i4)
        bpw[t] = i0 | (i1<<4) | (i2<<8) | (i3<<12) | (i4<<16);
      }
    }
    asm volatile("s_waitcnt vmcnt(0)" ::: "memory");   // bpw stores visible
    // ---- backtrack (unchanged, validated) ----
    {
      int tag = btag;
      for (int tb = TSEQ - 1; tb >= 1; tb -= 16){
        int w[16];
        #pragma unroll
        for (int i = 0; i < 16; i++){
          const int t = tb - i;
          w[i] = (t >= 1) ? bpw[t] : 0;
        }
        #pragma unroll
        for (int i = 0; i < 16; i++){
          const int t = tb - i;
          if (t >= 1){
            const int prev = (w[i] >> (tag*4)) & 15;
            if (lane == 0) out[t] = (float)prev;
            tag = prev;
          }
        }
      }
    }
    return;
  }

  if (blockIdx.x >= LSTM_WGS){
    // ================= inproj GEMM role =================
    float (*As)[132] = (float(*)[132])smem;              // 16 x 132
    float (*Bs)[132] = (float(*)[132])(smem + 8448);     // 16 x 132
    int* srow        = (int*)(smem + 16896);             // 128
    const int p   = blockIdx.x - LSTM_WGS;               // 0..1023
    const int ti  = p >> 5;                              // 0..31
    const int yy  = p & 31;                              // 0..31
    const int dir = yy >> 4;
    const int t_tile = dir ? (31 - ti) : ti;             // two-ended production
    const int t0  = t_tile * 128;
    const int n0  = (yy & 15) * 128;
    const float* __restrict__ W    = dir ? Wib : Wif;
    const float* __restrict__ bias = dir ? bb : bf;
    if (tid < 128) srow[tid] = sent[t0 + tid];
    __syncthreads();
    const int lr = tid >> 2;            // 0..127
    const int kq = (tid & 3) * 4;
    const float* ea = emb + (size_t)srow[lr]   * EMBD + kq;
    const float* wb = W + (size_t)(n0 + lr)    * EMBD + kq;
    const int tx = tid & 15, ty = tid >> 4;   // ty 0..31
    float acc[4][8];
    #pragma unroll
    for (int i = 0; i < 4; i++)
      #pragma unroll
      for (int j = 0; j < 8; j++) acc[i][j] = 0.f;

    for (int k0 = 0; k0 < EMBD; k0 += 16){
      float4 va = *(const float4*)(ea + k0);
      float4 vb = *(const float4*)(wb + k0);
      As[kq+0][lr] = va.x; As[kq+1][lr] = va.y; As[kq+2][lr] = va.z; As[kq+3][lr] = va.w;
      Bs[kq+0][lr] = vb.x; Bs[kq+1][lr] = vb.y; Bs[kq+2][lr] = vb.z; Bs[kq+3][lr] = vb.w;
      __syncthreads();
      #pragma unroll
      for (int k = 0; k < 16; k++){
        float a[4], b[8];
        *(float4*)&a[0] = *(const float4*)&As[k][ty*4];
        #pragma unroll
        for (int j = 0; j < 8; j++) b[j] = Bs[k][tx + 16*j];
        #pragma unroll
        for (int i = 0; i < 4; i++)
          #pragma unroll
          for (int j = 0; j < 8; j++)
            acc[i][j] = fmaf(a[i], b[j], acc[i][j]);
      }
      __syncthreads();
    }
    float bj[8];
    #pragma unroll
    for (int j = 0; j < 8; j++) bj[j] = bias[n0 + tx + 16*j];
    float* Abase = A + (size_t)dir * TSEQ * NGATE;
    #pragma unroll
    for (int i = 0; i < 4; i++){
      float* dst = Abase + (size_t)(t0 + ty*4 + i) * NGATE + n0 + tx;
      #pragma unroll
      for (int j = 0; j < 8; j++) dst[16*j] = acc[i][j] + bj[j];
    }
    __syncthreads();   // drains every wave's stores (HIP barrier semantics)
    if (tid == 0)
      __hip_atomic_fetch_add(&rdy[dir*32 + t_tile], 1,
                             __ATOMIC_RELEASE, __HIP_MEMORY_SCOPE_AGENT);
    return;
  }

  // ================= persistent lstm role =================
  float* hlbuf = (float*)smem;                 // [2][8*68] floats (4352B)
  float* gshp  = (float*)(smem + 4352);        // [16] h2 gather
  const int bid  = blockIdx.x;
  const int dir  = bid >> 5;
  const int wg   = bid & 31;
  const int lane = tid & 63;
  const int wv   = tid >> 6;        // wave 0..7 = slice index
  const int ul   = tid >> 5;        // unit local 0..15
  const int g    = (tid >> 3) & 3;  // gate i,f,g,o
  const int q    = tid & 7;         // column octant
  const int unit = wg*16 + ul;
  const float* __restrict__ Wh = dir ? Whb : Whf;

  float wreg[64];                   // Wh[g*512+unit][q*64 .. q*64+63]
  {
    const float* wr = Wh + (size_t)(g*HH + unit)*HH + q*64;
    #pragma unroll
    for (int j4 = 0; j4 < 16; j4++){
      float4 vv;
      // volatile load: result cannot be rematerialized -> stays in VGPRs
      asm volatile("global_load_dwordx4 %0, %1, off\n\t"
                   "s_waitcnt vmcnt(0)"
                   : "=v"(vv) : "v"(wr + 4*j4) : "memory");
      wreg[4*j4+0]=vv.x; wreg[4*j4+1]=vv.y; wreg[4*j4+2]=vv.z; wreg[4*j4+3]=vv.w;
    }
  }
  float creg = 0.f;
  if (g == 0 && q == 0) creg = c0[dir*HH + unit];

  u64* mb = hx2 + (size_t)dir*2*HH;
  const float* __restrict__ Ab = A + (size_t)dir*TSEQ*NGATE;
  const int sidx = (wv << 6) + lane;            // this wave's pair index

  // tile-gate + A prefetch for s=0
  int cur_tile = (dir ? (TSEQ - 1) : 0) >> 7;
  {
    const int* rf = rdy + dir*32 + cur_tile;
    while (__hip_atomic_load(rf, __ATOMIC_ACQUIRE, __HIP_MEMORY_SCOPE_AGENT) < 16)
      __builtin_amdgcn_s_sleep(2);
  }
  float av = 0.f;
  if (q == 0) av = Ab[(size_t)(dir ? (TSEQ - 1) : 0)*NGATE + g*HH + unit];

  for (int s = 0; s < TSEQ; s++){
    const int t = dir ? (TSEQ - 1 - s) : s;

    {  // every wave: poll own 64-pair slice (1 load/lane/round, masked reload)
      u64* src = mb + (size_t)(s & 1)*HH;
      const u32 su = (u32)s;
      u64 v = __hip_atomic_load(&src[sidx], __ATOMIC_RELAXED, __HIP_MEMORY_SCOPE_AGENT);
      while (!__all((u32)(v >> 32) == su)){
        if ((u32)(v >> 32) != su)
          v = __hip_atomic_load(&src[sidx], __ATOMIC_RELAXED, __HIP_MEMORY_SCOPE_AGENT);
      }
      hlbuf[(s & 1)*(8*68) + wv*68 + lane] = __uint_as_float((u32)v);
    }
    __syncthreads();

    // prefetch A for step s+1 (resolves under the matvec, off the poll path)
    float av_next = 0.f;
    if (s + 1 < TSEQ){
      const int t1 = dir ? (TSEQ - 2 - s) : (s + 1);
      const int tile1 = t1 >> 7;
      if (tile1 != cur_tile){
        cur_tile = tile1;
        const int* rf = rdy + dir*32 + tile1;
        while (__hip_atomic_load(rf, __ATOMIC_ACQUIRE, __HIP_MEMORY_SCOPE_AGENT) < 16)
          __builtin_amdgcn_s_sleep(2);
      }
      if (q == 0) av_next = Ab[(size_t)t1*NGATE + g*HH + unit];
    }

    // matvec: 64 FMAs from LDS chunk q (weights register-resident)
    const float* hq = hlbuf + (s & 1)*(8*68) + q*68;
    float p0 = 0.f, p1 = 0.f, p2 = 0.f, p3 = 0.f;
    #pragma unroll
    for (int j4 = 0; j4 < 16; j4++){
      float4 h4 = *(const float4*)(hq + 4*j4);
      p0 = fmaf(wreg[4*j4+0], h4.x, p0);
      p1 = fmaf(wreg[4*j4+1], h4.y, p1);
      p2 = fmaf(wreg[4*j4+2], h4.z, p2);
      p3 = fmaf(wreg[4*j4+3], h4.w, p3);
    }
    float acc = ((p0 + p1) + (p2 + p3)) + av;
    acc += __shfl_xor(acc, 1);
    acc += __shfl_xor(acc, 2);
    acc += __shfl_xor(acc, 4);
    // parallel nonlinearity: one transcendental per gate lane
    const float act = (g == 2) ? tanhf(acc) : sigm(acc);
    const float f_ = __shfl_down(act, 8);
    const float g_ = __shfl_down(act, 16);
    const float o_ = __shfl_down(act, 24);
    if (g == 0 && q == 0){
      const float c2 = f_*creg + act*g_;
      const float h2 = o_*tanhf(c2);
      creg = c2;
      gshp[ul] = h2;                 // gather h2 for coalesced publish
    }
    __syncthreads();                 // B2: gsh complete
    if (tid < 16){                   // wave 0: ONE coalesced 128B pair store/WG
      const float h2v = gshp[tid];
      __hip_atomic_store(&mb[(size_t)((s + 1) & 1)*HH + wg*16 + tid],
                         pack_pair(h2v, (u32)(s + 1)),
                         __ATOMIC_RELAXED, __HIP_MEMORY_SCOPE_AGENT);
      hseq[((size_t)dir*TSEQ + t)*HH + wg*16 + tid] = h2v;
    }
    av = av_next;
  }

  // ---------- feats epilogue: wait for all 64 lstm blocks, then 64 t-rows ------
  __syncthreads();   // all this block's hseq stores issued
  if (tid == 0)
    __hip_atomic_fetch_add(&rdy[65], 1, __ATOMIC_RELEASE, __HIP_MEMORY_SCOPE_AGENT);
  while (__hip_atomic_load(&rdy[65], __ATOMIC_ACQUIRE, __HIP_MEMORY_SCOPE_AGENT) < LSTM_WGS)
    __builtin_amdgcn_s_sleep(2);
  {
    const int wvi = tid >> 6;    // wave 0..7, each does 8 t values
    #pragma unroll
    for (int k = 0; k < 8; k++){
      const int t = bid*64 + wvi*8 + k;
      const float* hf = hseq + (size_t)t*HH;
      const float* hb = hseq + (size_t)(TSEQ + t)*HH;
      float x[16];
      #pragma unroll
      for (int j = 0; j < 8; j++) x[j]     = hf[lane + 64*j];
      #pragma unroll
      for (int j = 0; j < 8; j++) x[8 + j] = hb[lane + 64*j];
      #pragma unroll
      for (int n = 0; n < NTAGS; n++){
        const float* wr = Wout + (size_t)n*(2*HH);
        float p = 0.f;
        #pragma unroll
        for (int j = 0; j < 8; j++) p = fmaf(x[j],     wr[lane + 64*j],      p);
        #pragma unroll
        for (int j = 0; j < 8; j++) p = fmaf(x[8 + j], wr[HH + lane + 64*j], p);
        #pragma unroll
        for (int d = 1; d < 64; d <<= 1) p += __shfl_xor(p, d);
        if (lane == 0) feats[t*8 + n] = p + bout[n];
      }
    }
  }
  __syncthreads();   // all this block's feats stores issued
  if (tid == 0)
    __hip_atomic_fetch_add(&rdy[66], 1, __ATOMIC_RELEASE, __HIP_MEMORY_SCOPE_AGENT);
}

extern "C" void kernel_launch(void* const* d_in, const int* in_sizes, int n_in,
                              void* d_out, int out_size, void* d_ws, size_t ws_size,
                              hipStream_t stream) {
  const int*   sent = (const int*)  d_in[0];
  const float* emb  = (const float*)d_in[1];
  const float* Wihf = (const float*)d_in[2];
  const float* Whhf = (const float*)d_in[3];
  const float* bf_  = (const float*)d_in[4];
  const float* Wihb = (const float*)d_in[5];
  const float* Whhb = (const float*)d_in[6];
  const float* bb_  = (const float*)d_in[7];
  const float* Wout = (const float*)d_in[8];
  const float* bout = (const float*)d_in[9];
  const float* trans= (const float*)d_in[10];
  const float* h0   = (const float*)d_in[11];
  const float* c0   = (const float*)d_in[12];
  float* out = (float*)d_out;

  float* ws   = (float*)d_ws;
  float* A    = ws;                                  // [2][T][2048]
  float* hseq = A    + (size_t)2*TSEQ*NGATE;         // [2][T][512]
  u64*   hx2  = (u64*)(hseq + (size_t)2*TSEQ*HH);    // [2][2][512] (tag,val) pairs
  float* fe   = (float*)(hx2 + 2048);                // [T][8]
  int*   bpw  = (int*)(fe + (size_t)TSEQ*8);         // [T] packed nibbles
  int*   rdy  = bpw + TSEQ;                          // [64] tile-ready + [65][66]
  float* fvh  = (float*)(rdy + 96);                  // [T+1][5] fv history
  (void)ws_size;

  k_init<<<1, 1024, 0, stream>>>(h0, hx2, rdy);
  k_fused<<<VIT_BLOCK + 1, 512, 0, stream>>>(
      sent, emb, Wihf, bf_, Wihb, bb_, Whhf, Whhb, c0, Wout, bout, trans,
      A, hseq, fe, bpw, fvh, out, hx2, rdy);
}